// Round 5
// baseline (917.772 us; speedup 1.0000x reference)
//
#include <hip/hip_runtime.h>
#include <math.h>

// ---------------------------------------------------------------------------
// Round 14: resubmit r13 (persistent batch-split LSTM, zero synchronization)
// after infra failure, with one hardening change: the kk-loop is pinned to
// #pragma unroll 2 so the compiler cannot fully unroll (14x) and blow the
// <=256 VGPR budget with 168 in-flight global B-loads (scratch spill risk).
// Structure: one block owns 32 batch rows x ALL 1536 gate cols x 14 steps.
// h lives in the block's LDS A-buffer (32x456), c in registers -> no grid
// barrier, no coop launch, no coherence ops. Weights (2.6 MB, L2-resident
// per XCD) stream straight to B-fragments in registers. 256 blocks = 1/CU.
// ---------------------------------------------------------------------------

using bf16x8 = __attribute__((ext_vector_type(8))) short;
using f32x4  = __attribute__((ext_vector_type(4))) float;

enum { EPI_NONE = 0, EPI_RELU = 1, EPI_TANH = 2 };

__device__ inline unsigned short f2bf(float f) {
    union { float f; unsigned u; } v; v.f = f;
    unsigned r = v.u + 0x7FFFu + ((v.u >> 16) & 1u);
    return (unsigned short)(r >> 16);
}
__device__ inline float sigf(float x) {
    return __fdividef(1.f, 1.f + __expf(-x));
}
__device__ inline float tanhfast(float x) {
    return 1.f - __fdividef(2.f, 1.f + __expf(2.f * x));
}

__device__ inline void gll16(const void* g, void* l) {
    __builtin_amdgcn_global_load_lds(
        (const __attribute__((address_space(1))) unsigned int*)(uintptr_t)g,
        (__attribute__((address_space(3))) unsigned int*)(unsigned int)(uintptr_t)l,
        16, 0, 0);
}

// ---------------------------------------------------------------------------
// Persistent LSTM: grid 256 x 512 threads. Block b owns batch rows
// [32b, 32b+32). A-buffer [32][456] bf16 in LDS (448 cols + 8 pad shorts).
// Wave w owns packed gate cols [192w, 192w+192) = units {48w..48w+47}.
// Packed col layout (from pack_lstm2): n' = (u>>4)*64 + g*16 + (u&15).
// ---------------------------------------------------------------------------
#define PROWS 32
#define PLDA  456

__global__ __launch_bounds__(512, 2)
void lstm_persist(const float* __restrict__ x,
                  const float* __restrict__ m,
                  const unsigned short* __restrict__ WtE,
                  const unsigned short* __restrict__ WtD,
                  const float* __restrict__ bIE,
                  const float* __restrict__ bID,
                  unsigned short* __restrict__ dcd)
{
    __shared__ __attribute__((aligned(16))) unsigned short Ab[PROWS * PLDA];
    const int tid  = threadIdx.x;
    const int lane = tid & 63;
    const int w    = tid >> 6;           // 0..7
    const int lm   = lane & 15, quad = lane >> 4;
    const int brow = blockIdx.x * PROWS;

    // zero A-buffer (pads stay 0 forever), then stage x slice t=0
    for (int i = tid; i < PROWS * PLDA; i += 512) Ab[i] = 0;
    __syncthreads();
    for (int i = tid; i < PROWS * 69; i += 512) {
        const int r = i / 69, f = i - r * 69;
        Ab[r * PLDA + f] = f2bf(x[((size_t)(brow + r) * 7 + 0) * 69 + f]);
    }

    float creg[2][3][4] = {};   // cell state: [mi][a][r] for unit (3w+a)*16+lm
    float bI[3][4];             // bias: [a][gate]

    for (int s = 0; s < 14; ++s) {
        const bool enc = (s < 7);
        const int t = enc ? s : s - 7;
        const unsigned short* Wt = enc ? WtE : WtD;
        const unsigned short* wbase =
            Wt + (size_t)(w * 192 + lm) * 448 + quad * 8;

        if (s == 0 || s == 7) {
            const float* bsrc = enc ? bIE : bID;
            #pragma unroll
            for (int a = 0; a < 3; ++a)
                #pragma unroll
                for (int g = 0; g < 4; ++g)
                    bI[a][g] = bsrc[(3 * w + a) * 64 + g * 16 + lm];
        }

        __syncthreads();   // Ab (x for s, h from s-1) fully written

        f32x4 acc[2][12] = {};
        #pragma unroll 2
        for (int kk = 0; kk < 14; ++kk) {
            bf16x8 aF[2];
            #pragma unroll
            for (int mi = 0; mi < 2; ++mi)
                aF[mi] = *(const bf16x8*)&Ab[(mi * 16 + lm) * PLDA
                                             + kk * 32 + quad * 8];
            bf16x8 bF[12];
            #pragma unroll
            for (int ni = 0; ni < 12; ++ni)
                bF[ni] = *(const bf16x8*)(wbase + (size_t)ni * 16 * 448
                                          + kk * 32);
            #pragma unroll
            for (int ni = 0; ni < 12; ++ni) {
                acc[0][ni] = __builtin_amdgcn_mfma_f32_16x16x32_bf16(
                    aF[0], bF[ni], acc[0][ni], 0, 0, 0);
                acc[1][ni] = __builtin_amdgcn_mfma_f32_16x16x32_bf16(
                    aF[1], bF[ni], acc[1][ni], 0, 0, 0);
            }
        }

        __syncthreads();   // all Ab reads done before h overwrite

        // epilogue: gates -> c (regs) -> h -> Ab[hoff+u] (+ dcd in dec phase)
        const int hoff = (s < 6) ? 69 : 45;   // layout of step s+1
        #pragma unroll
        for (int mi = 0; mi < 2; ++mi)
            #pragma unroll
            for (int a = 0; a < 3; ++a) {
                const int u = (3 * w + a) * 16 + lm;
                const bool uok = (u < 356);
                #pragma unroll
                for (int r = 0; r < 4; ++r) {
                    const float zi = acc[mi][a * 4 + 0][r] + bI[a][0];
                    const float zf = acc[mi][a * 4 + 1][r] + bI[a][1];
                    const float zg = acc[mi][a * 4 + 2][r] + bI[a][2];
                    const float zo = acc[mi][a * 4 + 3][r] + bI[a][3];
                    const float cn = sigf(zf) * creg[mi][a][r]
                                   + sigf(zi) * tanhfast(zg);
                    creg[mi][a][r] = cn;
                    const unsigned short hb = f2bf(sigf(zo) * tanhfast(cn));
                    const int rl = mi * 16 + quad * 4 + r;
                    if (uok) {
                        if (s < 13) Ab[rl * PLDA + hoff + u] = hb;
                        if (!enc)
                            dcd[(size_t)(brow + rl) * 2496 + t * 356 + u] = hb;
                    }
                }
            }

        // stage x/m slice for step s+1 (disjoint from h region)
        const int sn = s + 1;
        if (sn < 7) {
            for (int i = tid; i < PROWS * 69; i += 512) {
                const int r = i / 69, f = i - r * 69;
                Ab[r * PLDA + f] =
                    f2bf(x[((size_t)(brow + r) * 7 + sn) * 69 + f]);
            }
        } else if (sn < 14) {
            for (int i = tid; i < PROWS * 45; i += 512) {
                const int r = i / 45, f = i - r * 45;
                Ab[r * PLDA + f] =
                    f2bf(m[((size_t)(brow + r) * 7 + (sn - 7)) * 45 + f]);
            }
        }
    }
}

// ---- MLP GEMM machinery (unchanged, proven) ----

#define STAGE(A_, Bt_, K_, k0_, b_)                                            \
    {                                                                          \
        const int row = tid >> 2, kc = tid & 3;                                \
        gll16((A_)  + (size_t)(m0 + row) * (K_) + (k0_) + kc * 8,              \
              (void*)&As[b_][tid * 8]);                                        \
        gll16((Bt_) + (size_t)(n0 + row) * (K_) + (k0_) + kc * 8,              \
              (void*)&Bs[b_][tid * 8]);                                        \
    }

#define GEMM_CORE(A_, Bt_, K_)                                                 \
    STAGE(A_, Bt_, K_, 0, 0)                                                   \
    {                                                                          \
        const int niter = (K_) / 32;                                           \
        for (int it = 0; it < niter; ++it) {                                   \
            __syncthreads();                                                   \
            if (it + 1 < niter) {                                              \
                const int kn = (it + 1) * 32, bn = (it + 1) & 1;               \
                STAGE(A_, Bt_, K_, kn, bn)                                     \
            }                                                                  \
            const unsigned short* Asb = As[it & 1];                            \
            const unsigned short* Bsb = Bs[it & 1];                            \
            bf16x8 aF[2], bF[4];                                               \
            _Pragma("unroll")                                                  \
            for (int mi = 0; mi < 2; ++mi)                                     \
                aF[mi] = *(const bf16x8*)(Asb + (wr*32 + mi*16 + lm)*32 + quad*8);\
            _Pragma("unroll")                                                  \
            for (int ni = 0; ni < 4; ++ni)                                     \
                bF[ni] = *(const bf16x8*)(Bsb + (wc*64 + ni*16 + lm)*32 + quad*8);\
            _Pragma("unroll")                                                  \
            for (int mi = 0; mi < 2; ++mi)                                     \
                _Pragma("unroll")                                              \
                for (int ni = 0; ni < 4; ++ni)                                 \
                    acc[mi][ni] = __builtin_amdgcn_mfma_f32_16x16x32_bf16(     \
                        aF[mi], bF[ni], acc[mi][ni], 0, 0, 0);                 \
        }                                                                      \
    }

#define GEMM_PREAMBLE                                                          \
    __shared__ __attribute__((aligned(16))) unsigned short As[2][128 * 32];    \
    __shared__ __attribute__((aligned(16))) unsigned short Bs[2][128 * 32];    \
    const int tid  = threadIdx.x;                                              \
    const int lane = tid & 63;                                                 \
    const int w    = tid >> 6;          /* 0..7 */                             \
    const int wr   = w >> 1, wc = w & 1; /* 4x2 wave grid */                   \
    const int lm   = lane & 15, quad = lane >> 4;                              \
    const int m0   = blockIdx.x * 128, n0 = blockIdx.y * 128;                  \
    f32x4 acc[2][4] = {};

template <int EPI, int OUT_BF16, int NGUARD>
__global__ __launch_bounds__(512, 6)
void gemm_mfma(const unsigned short* __restrict__ A,
               const unsigned short* __restrict__ Bt,
               const float* __restrict__ bias,
               void* __restrict__ Cv, int ldc, int Nreal, int K)
{
    GEMM_PREAMBLE
    GEMM_CORE(A, Bt, K)
    #pragma unroll
    for (int mi = 0; mi < 2; ++mi)
        #pragma unroll
        for (int r = 0; r < 4; ++r) {
            const size_t row = m0 + wr * 32 + mi * 16 + quad * 4 + r;
            #pragma unroll
            for (int ni = 0; ni < 4; ++ni) {
                const int col = n0 + wc * 64 + ni * 16 + lm;
                if (!NGUARD || col < Nreal) {
                    float v = acc[mi][ni][r] + bias[col];
                    if (EPI == EPI_RELU) v = fmaxf(v, 0.f);
                    if (EPI == EPI_TANH) v = tanhfast(v);
                    if (OUT_BF16) ((unsigned short*)Cv)[row * ldc + col] = f2bf(v);
                    else          ((float*)Cv)[row * ldc + col] = v;
                }
            }
        }
}

// ---- LSTM weight pack (enc+dec in one launch; blockIdx.y selects) ----
// dec packed to Kp=448 (zeros k>=401) so persist kernel uses K=448 always.
struct PackArgs {
    const float *Wa0, *Wb0, *bias0; unsigned short* Wt0; float* bI0; int K10, K0, Kp0;
    const float *Wa1, *Wb1, *bias1; unsigned short* Wt1; float* bI1; int K11, K1, Kp1;
};
__global__ void pack_lstm2(PackArgs p)
{
    const float* Wa  = blockIdx.y ? p.Wa1  : p.Wa0;
    const float* Wb  = blockIdx.y ? p.Wb1  : p.Wb0;
    const float* bias= blockIdx.y ? p.bias1: p.bias0;
    unsigned short* Wt = blockIdx.y ? p.Wt1 : p.Wt0;
    float* biasI = blockIdx.y ? p.bI1 : p.bI0;
    const int K1 = blockIdx.y ? p.K11 : p.K10;
    const int K  = blockIdx.y ? p.K1  : p.K0;
    const int Kp = blockIdx.y ? p.Kp1 : p.Kp0;
    const int idx = blockIdx.x * 256 + threadIdx.x;
    if (idx >= 1536 * Kp) return;
    const int np = idx / Kp, k = idx - np * Kp;
    const int ub = np >> 6, g = (np >> 4) & 3, ul = np & 15;
    const int u = ub * 16 + ul;
    const bool valid = (u < 356);
    const int norig = g * 356 + u;
    float v = 0.f;
    if (valid && k < K)
        v = (k < K1) ? Wa[(size_t)k * 1424 + norig]
                     : Wb[(size_t)(k - K1) * 1424 + norig];
    Wt[(size_t)np * Kp + k] = f2bf(v);
    if (k == 0) biasI[np] = valid ? bias[norig] : 0.f;
}

// ---- MLP weight transpose+pack (fp32 [K][N] -> bf16 [Np][Kp]) ----
__global__ void transpose_pack(const float* __restrict__ W, int K, int N,
                               unsigned short* __restrict__ Wt, int Kp, int Np)
{
    __shared__ float t[32][33];
    const int n0 = blockIdx.x * 32, k0 = blockIdx.y * 32;
    const int tx = threadIdx.x, ty = threadIdx.y;
    #pragma unroll
    for (int r = 0; r < 4; ++r) {
        const int k = k0 + ty + 8 * r, n = n0 + tx;
        t[ty + 8 * r][tx] = (k < K && n < N) ? W[(size_t)k * N + n] : 0.f;
    }
    __syncthreads();
    #pragma unroll
    for (int r = 0; r < 4; ++r) {
        const int k = k0 + tx, n = n0 + ty + 8 * r;
        if (k < Kp && n < Np) Wt[(size_t)n * Kp + k] = f2bf(t[tx][ty + 8 * r]);
    }
}

// three 1024x1024 transposes in one launch (blockIdx.z selects)
struct WP3 { const float *s0, *s1, *s2; unsigned short *d0, *d1, *d2; };
__global__ void transpose_pack3(WP3 p)
{
    __shared__ float t[32][33];
    const float* W = (blockIdx.z == 0) ? p.s0 : (blockIdx.z == 1) ? p.s1 : p.s2;
    unsigned short* Wt = (blockIdx.z == 0) ? p.d0 : (blockIdx.z == 1) ? p.d1 : p.d2;
    const int n0 = blockIdx.x * 32, k0 = blockIdx.y * 32;
    const int tx = threadIdx.x, ty = threadIdx.y;
    #pragma unroll
    for (int r = 0; r < 4; ++r)
        t[ty + 8 * r][tx] = W[(size_t)(k0 + ty + 8 * r) * 1024 + n0 + tx];
    __syncthreads();
    #pragma unroll
    for (int r = 0; r < 4; ++r)
        Wt[(size_t)(n0 + ty + 8 * r) * 1024 + k0 + tx] = f2bf(t[tx][ty + 8 * r]);
}

// ---- zero dcd pad cols (2492..2495 of each row) ----
__global__ void zero_dcd_pad(unsigned short* __restrict__ dcd)
{
    const int i = blockIdx.x * 256 + threadIdx.x;
    if (i < 8192 * 4) dcd[(size_t)(i >> 2) * 2496 + 2492 + (i & 3)] = 0;
}

extern "C" void kernel_launch(void* const* d_in, const int* in_sizes, int n_in,
                              void* d_out, int out_size, void* d_ws, size_t ws_size,
                              hipStream_t stream)
{
    const float* x     = (const float*)d_in[0];
    const float* m     = (const float*)d_in[1];
    const float* enc_W = (const float*)d_in[2];
    const float* enc_U = (const float*)d_in[3];
    const float* enc_b = (const float*)d_in[4];
    const float* dec_W = (const float*)d_in[5];
    const float* dec_Um= (const float*)d_in[6];
    const float* dec_b = (const float*)d_in[7];
    const float* W_map = (const float*)d_in[8];
    const float* b_map = (const float*)d_in[9];
    const float* W1    = (const float*)d_in[10];
    const float* b1    = (const float*)d_in[11];
    const float* W2    = (const float*)d_in[12];
    const float* b2    = (const float*)d_in[13];
    const float* W3    = (const float*)d_in[14];
    const float* b3    = (const float*)d_in[15];
    const float* W_out = (const float*)d_in[16];
    const float* b_out = (const float*)d_in[17];
    float* out = (float*)d_out;

    const int B = 8192, FE = 69, FD = 45;
    const int KMP = 2496;

    char* ws = (char*)d_ws;
    size_t off = 0;
    auto alloc = [&](size_t bytes) -> void* {
        void* p = ws + off; off = (off + bytes + 255) & ~(size_t)255; return p;
    };
    unsigned short* WtE = (unsigned short*)alloc((size_t)1536 * 448 * 2);
    unsigned short* WtD = (unsigned short*)alloc((size_t)1536 * 448 * 2);
    unsigned short* WtM = (unsigned short*)alloc((size_t)1024 * KMP * 2);
    unsigned short* Wt1 = (unsigned short*)alloc((size_t)1024 * 1024 * 2);
    unsigned short* Wt2 = (unsigned short*)alloc((size_t)1024 * 1024 * 2);
    unsigned short* Wt3 = (unsigned short*)alloc((size_t)1024 * 1024 * 2);
    unsigned short* WtO = (unsigned short*)alloc((size_t)256 * 1024 * 2);
    float* bIE = (float*)alloc(1536 * 4);
    float* bID = (float*)alloc(1536 * 4);
    unsigned short* dcd = (unsigned short*)alloc((size_t)B * KMP * 2);
    unsigned short* a1  = (unsigned short*)alloc((size_t)B * 1024 * 2);
    unsigned short* a2  = (unsigned short*)alloc((size_t)B * 1024 * 2);

    // ---- weight packing (both LSTMs padded to Kp=448) ----
    PackArgs pa{enc_W, enc_U, enc_b, WtE, bIE, FE, FE + 356, 448,
                dec_W, dec_Um, dec_b, WtD, bID, FD, FD + 356, 448};
    pack_lstm2<<<dim3((1536 * 448 + 255) / 256, 2), 256, 0, stream>>>(pa);
    const dim3 tb(32, 8);
    transpose_pack<<<dim3(1024 / 32, KMP / 32), tb, 0, stream>>>(
        W_map, 2492, 1024, WtM, KMP, 1024);
    WP3 p3{W1, W2, W3, Wt1, Wt2, Wt3};
    transpose_pack3<<<dim3(32, 32, 3), tb, 0, stream>>>(p3);
    transpose_pack<<<dim3(256 / 32, 1024 / 32), tb, 0, stream>>>(
        W_out, 1024, 168, WtO, 1024, 256);
    zero_dcd_pad<<<(8192 * 4 + 255) / 256, 256, 0, stream>>>(dcd);

    // ---- persistent LSTM: one plain launch, zero barriers ----
    lstm_persist<<<256, 512, 0, stream>>>(x, m, WtE, WtD, bIE, bID, dcd);

    // ---- MLP head ----
    gemm_mfma<EPI_RELU, 1, 0><<<dim3(64, 8), 512, 0, stream>>>(
        dcd, WtM, b_map, a1, 1024, 1024, KMP);
    gemm_mfma<EPI_TANH, 1, 0><<<dim3(64, 8), 512, 0, stream>>>(
        a1, Wt1, b1, a2, 1024, 1024, 1024);
    gemm_mfma<EPI_TANH, 1, 0><<<dim3(64, 8), 512, 0, stream>>>(
        a2, Wt2, b2, a1, 1024, 1024, 1024);
    gemm_mfma<EPI_TANH, 1, 0><<<dim3(64, 8), 512, 0, stream>>>(
        a1, Wt3, b3, a2, 1024, 1024, 1024);
    gemm_mfma<EPI_NONE, 0, 1><<<dim3(64, 2), 512, 0, stream>>>(
        a2, WtO, b_out, out, 168, 168, 1024);
}